// Round 13
// baseline (445.082 us; speedup 1.0000x reference)
//
#include <hip/hip_runtime.h>
#include <cstdint>

typedef __attribute__((ext_vector_type(8))) __bf16 bf16x8;
typedef __attribute__((ext_vector_type(4))) __bf16 bf16x4;
typedef __attribute__((ext_vector_type(4))) float f32x4;

#define S_LEN 2048
#define NH 16
#define DMODEL 1024
#define M_ROWS 8192

// async global->LDS, 16B per lane; LDS dest must be wave-uniform base.
__device__ __forceinline__ void gload16(const void* g, void* l) {
  __builtin_amdgcn_global_load_lds(
      (const __attribute__((address_space(1))) void*)const_cast<void*>(g),
      (__attribute__((address_space(3))) void*)l, 16, 0, 0);
}

// ---------------------------------------------------------------------------
// x (fp32) -> x_hi + x_lo (bf16 split)
// ---------------------------------------------------------------------------
__global__ __launch_bounds__(256) void split_x_kernel(
    const float* __restrict__ in, __bf16* __restrict__ hi, __bf16* __restrict__ lo)
{
  const size_t i = ((size_t)blockIdx.x * 256 + threadIdx.x) * 4;
  const float4 v = *(const float4*)(in + i);
  const float vv[4] = {v.x, v.y, v.z, v.w};
  bf16x4 h, l;
#pragma unroll
  for (int j = 0; j < 4; ++j) {
    const __bf16 hb = (__bf16)vv[j];
    h[j] = hb;
    l[j] = (__bf16)(vv[j] - (float)hb);
  }
  *(bf16x4*)(hi + i) = h;
  *(bf16x4*)(lo + i) = l;
}

// ---------------------------------------------------------------------------
// W[k][n] (fp32) -> Wt_hi[n][k], Wt_lo[n][k] (bf16 split, transposed)
// ---------------------------------------------------------------------------
__global__ __launch_bounds__(256) void tsplit_w_kernel(
    const float* __restrict__ W, __bf16* __restrict__ th, __bf16* __restrict__ tl)
{
  __shared__ float tile[32][33];
  const int t = threadIdx.x;
  const int n0 = blockIdx.x * 32, k0 = blockIdx.y * 32;
  {
    const int r = t >> 3, c = (t & 7) * 4;
    const float4 v = *(const float4*)(W + (size_t)(k0 + r) * DMODEL + n0 + c);
    tile[r][c] = v.x; tile[r][c + 1] = v.y; tile[r][c + 2] = v.z; tile[r][c + 3] = v.w;
  }
  __syncthreads();
  const int n = t >> 3, kk = (t & 7) * 4;
  bf16x4 h, l;
#pragma unroll
  for (int j = 0; j < 4; ++j) {
    const float v = tile[kk + j][n];
    const __bf16 hb = (__bf16)v;
    h[j] = hb;
    l[j] = (__bf16)(v - (float)hb);
  }
  *(bf16x4*)(th + (size_t)(n0 + n) * DMODEL + k0 + kk) = h;
  *(bf16x4*)(tl + (size_t)(n0 + n) * DMODEL + k0 + kk) = l;
}

// ---------------------------------------------------------------------------
// bf16x3 split-precision GEMM: C = (Ah+Al)[M,1024] * (Bh+Bl)^T[n][k] + bias
// 128x128 tile, BK=32, 4 waves, per-wave 64x64 (4x4 frags of 16x16x32 MFMA).
// mode 0: fp32 out [m][n];  mode 1: bf16 headsplit [b,h,s,d] (*scale);
// mode 2: bf16 transposed-V [b,h,d,s].
// ---------------------------------------------------------------------------
__global__ __launch_bounds__(256) void gemm_bf16x3_kernel(
    const __bf16* __restrict__ Ah, const __bf16* __restrict__ Al,
    const __bf16* __restrict__ Bh, const __bf16* __restrict__ Bl,
    const float* __restrict__ bias, float* __restrict__ outF,
    __bf16* __restrict__ outB, const int mode, const float scale)
{
  __shared__ __align__(16) __bf16 sAh[128 * 32];
  __shared__ __align__(16) __bf16 sAl[128 * 32];
  __shared__ __align__(16) __bf16 sBh[128 * 32];
  __shared__ __align__(16) __bf16 sBl[128 * 32];

  const int tid = threadIdx.x;
  const int w = tid >> 6, l = tid & 63;
  const int wr = w >> 1, wc = w & 1;
  const int m0 = blockIdx.x * 128, n0 = blockIdx.y * 128;
  const int q = l & 15, kg = l >> 4;

  f32x4 acc[4][4];
#pragma unroll
  for (int i = 0; i < 4; ++i)
#pragma unroll
    for (int j = 0; j < 4; ++j) acc[i][j] = f32x4{0.f, 0.f, 0.f, 0.f};

  const int sr0 = w * 32 + (l >> 2);  // staging row (u adds 16)
  const int sg = l & 3;               // staging granule (16B units within 64B row)

  for (int k0 = 0; k0 < 1024; k0 += 32) {
    __syncthreads();
#pragma unroll
    for (int u = 0; u < 2; ++u) {
      const int r = sr0 + u * 16;
      const int gs = sg ^ ((r >> 1) & 3);  // pre-swizzled source granule
      const size_t offA = (size_t)(m0 + r) * 1024 + k0 + gs * 8;
      const size_t offB = (size_t)(n0 + r) * 1024 + k0 + gs * 8;
      const int ldsoff = w * 2048 + u * 1024;  // wave-uniform
      gload16(Ah + offA, (char*)sAh + ldsoff);
      gload16(Al + offA, (char*)sAl + ldsoff);
      gload16(Bh + offB, (char*)sBh + ldsoff);
      gload16(Bl + offB, (char*)sBl + ldsoff);
    }
    __syncthreads();

    bf16x8 fah[4], fal[4], fbh[4], fbl[4];
#pragma unroll
    for (int mf = 0; mf < 4; ++mf) {
      const int row = wr * 64 + mf * 16 + q;
      const int off = row * 64 + ((kg ^ ((row >> 1) & 3)) * 16);
      fah[mf] = *(const bf16x8*)((const char*)sAh + off);
      fal[mf] = *(const bf16x8*)((const char*)sAl + off);
    }
#pragma unroll
    for (int nf = 0; nf < 4; ++nf) {
      const int n = wc * 64 + nf * 16 + q;
      const int off = n * 64 + ((kg ^ ((n >> 1) & 3)) * 16);
      fbh[nf] = *(const bf16x8*)((const char*)sBh + off);
      fbl[nf] = *(const bf16x8*)((const char*)sBl + off);
    }
#pragma unroll
    for (int mf = 0; mf < 4; ++mf)
#pragma unroll
      for (int nf = 0; nf < 4; ++nf) {
        acc[mf][nf] = __builtin_amdgcn_mfma_f32_16x16x32_bf16(fah[mf], fbh[nf], acc[mf][nf], 0, 0, 0);
        acc[mf][nf] = __builtin_amdgcn_mfma_f32_16x16x32_bf16(fah[mf], fbl[nf], acc[mf][nf], 0, 0, 0);
        acc[mf][nf] = __builtin_amdgcn_mfma_f32_16x16x32_bf16(fal[mf], fbh[nf], acc[mf][nf], 0, 0, 0);
      }
  }

  // epilogue: C/D layout col = lane&15, row = (lane>>4)*4 + reg
#pragma unroll
  for (int mf = 0; mf < 4; ++mf) {
#pragma unroll
    for (int nf = 0; nf < 4; ++nf) {
      const int nloc = wc * 64 + nf * 16 + q;
      const int n = n0 + nloc;
      const float bv = bias[n];
      const int mbase = m0 + wr * 64 + mf * 16 + kg * 4;
      if (mode == 0) {
#pragma unroll
        for (int r = 0; r < 4; ++r)
          outF[(size_t)(mbase + r) * 1024 + n] = acc[mf][nf][r] + bv;
      } else if (mode == 1) {
#pragma unroll
        for (int r = 0; r < 4; ++r) {
          const int m = mbase + r;
          const int b = m >> 11, s = m & 2047, h = n >> 6, d = n & 63;
          outB[(((size_t)(b * NH + h)) * S_LEN + s) * 64 + d] =
              (__bf16)((acc[mf][nf][r] + bv) * scale);
        }
      } else {
        const int b = mbase >> 11, s0 = mbase & 2047, h = n >> 6, d = n & 63;
        bf16x4 pv;
#pragma unroll
        for (int r = 0; r < 4; ++r) pv[r] = (__bf16)(acc[mf][nf][r] + bv);
        *(bf16x4*)(outB + (((size_t)(b * NH + h)) * 64 + d) * S_LEN + s0) = pv;
      }
    }
  }
}

// ---------------------------------------------------------------------------
// Flash attention, bf16 MFMA, fixed-shift softmax, DOUBLE-BUFFERED staging.
// Block = 128 q-rows of one (b,h); 4 waves x 32 q-rows (2 groups of 16).
// Per tile: STAGE(next tile, other buffer) -> compute(cur) -> syncthreads.
// The __syncthreads() vmcnt drain covers the staged loads; staging latency
// hides under ~500 cyc of MFMA+softmax (T3 minimum 2-phase recipe).
// ---------------------------------------------------------------------------
__global__ __launch_bounds__(256) void attn_mfma_kernel(
    const __bf16* __restrict__ qbuf, const __bf16* __restrict__ kbuf,
    const __bf16* __restrict__ vbufT, __bf16* __restrict__ o_hi,
    __bf16* __restrict__ o_lo)
{
  __shared__ __align__(16) __bf16 Ks[2][64 * 64];     // [buf][kv][d], swizzled
  __shared__ __align__(16) __bf16 Vt[2][64 * 64];     // [buf][d][kv], swizzled
  __shared__ __align__(16) __bf16 Pt[4 * 32 * 64];    // per-wave [q][kv], swizzled

  const int tid = threadIdx.x;
  const int w = tid >> 6, l = tid & 63;
  const int q = l & 15, kg = l >> 4;
  const int q7 = q & 7;
  const int bh = blockIdx.y;
  const int q0 = blockIdx.x * 128;

  // Q fragments in registers (B-operand: col=q, k=d contiguous 8)
  bf16x8 qf[2][2];
#pragma unroll
  for (int qg = 0; qg < 2; ++qg) {
    const __bf16* qp =
        qbuf + ((size_t)bh * S_LEN + q0 + w * 32 + qg * 16 + q) * 64 + kg * 8;
    qf[qg][0] = *(const bf16x8*)qp;
    qf[qg][1] = *(const bf16x8*)(qp + 32);
  }

  float l_s[2] = {0.f, 0.f};
  f32x4 acc_o[2][4];
#pragma unroll
  for (int qg = 0; qg < 2; ++qg)
#pragma unroll
    for (int i = 0; i < 4; ++i) acc_o[qg][i] = f32x4{0.f, 0.f, 0.f, 0.f};

  char* const Pw = (char*)Pt + w * 4096;
  const int sr = w * 16 + (l >> 3);  // staging row (u adds 8)
  const int sg = l & 7;              // granule (16B units within 128B row)

  // hoisted swizzled fragment offsets (kv&7 == q&7 and d&7 == q&7 patterns)
  const int koff0 = q * 128 + ((kg ^ q7) << 4);          // Ks frag, kf=0
  const int koff1 = q * 128 + (((kg + 4) ^ q7) << 4);    // Ks frag, kf=1
  int voff[2];   // Vt / P-read granule offsets per kf chunk
#pragma unroll
  for (int kf = 0; kf < 2; ++kf) voff[kf] = ((kf * 4 + kg) ^ q7) << 4;

  // issue async staging of tile t into buffer buf
  auto STAGE = [&](int buf, int t) {
#pragma unroll
    for (int u = 0; u < 2; ++u) {
      const int r = sr + u * 8;
      const int gs = sg ^ (r & 7);
      const int ldsoff = w * 2048 + u * 1024;
      gload16(kbuf + ((size_t)bh * S_LEN + t * 64 + r) * 64 + gs * 8,
              (char*)Ks[buf] + ldsoff);
      gload16(vbufT + ((size_t)bh * 64 + r) * S_LEN + t * 64 + gs * 8,
              (char*)Vt[buf] + ldsoff);
    }
  };

  // compute one 64-kv tile from the given buffers
  auto COMPUTE = [&](const __bf16* Ksb, const __bf16* Vtb) {
    // scores S^T[kv][q] for both q-groups (K frags reused)
    f32x4 sacc[2][4];
#pragma unroll
    for (int qg = 0; qg < 2; ++qg)
#pragma unroll
      for (int mf = 0; mf < 4; ++mf) sacc[qg][mf] = f32x4{0.f, 0.f, 0.f, 0.f};

    __builtin_amdgcn_s_setprio(1);
#pragma unroll
    for (int mf = 0; mf < 4; ++mf) {
      const bf16x8 a0 = *(const bf16x8*)((const char*)Ksb + mf * 2048 + koff0);
      const bf16x8 a1 = *(const bf16x8*)((const char*)Ksb + mf * 2048 + koff1);
#pragma unroll
      for (int qg = 0; qg < 2; ++qg) {
        sacc[qg][mf] = __builtin_amdgcn_mfma_f32_16x16x32_bf16(a0, qf[qg][0], sacc[qg][mf], 0, 0, 0);
        sacc[qg][mf] = __builtin_amdgcn_mfma_f32_16x16x32_bf16(a1, qf[qg][1], sacc[qg][mf], 0, 0, 0);
      }
    }
    __builtin_amdgcn_s_setprio(0);

    // p = exp2(s); accumulate per-lane l; store P bf16 to per-wave LDS
#pragma unroll
    for (int qg = 0; qg < 2; ++qg) {
      float ps = l_s[qg];
#pragma unroll
      for (int mf = 0; mf < 4; ++mf) {
        bf16x4 pv;
#pragma unroll
        for (int r = 0; r < 4; ++r) {
          const float p = exp2f(sacc[qg][mf][r]);
          ps += p;
          pv[r] = (__bf16)p;
        }
        *(bf16x4*)(Pw + (qg * 16 + q) * 128 + ((mf * 32 + kg * 8) ^ (q7 << 4))) = pv;
      }
      l_s[qg] = ps;
    }

    // PV: O[q][d] += P[q][kv] * V[kv][d]  (V frags reused across q-groups)
    bf16x8 pa[2][2];
#pragma unroll
    for (int qg = 0; qg < 2; ++qg)
#pragma unroll
      for (int kf = 0; kf < 2; ++kf)
        pa[qg][kf] = *(const bf16x8*)(Pw + (qg * 16 + q) * 128 + voff[kf]);

    __builtin_amdgcn_s_setprio(1);
#pragma unroll
    for (int nf = 0; nf < 4; ++nf) {
      const bf16x8 vb0 = *(const bf16x8*)((const char*)Vtb + nf * 2048 + q * 128 + voff[0]);
      const bf16x8 vb1 = *(const bf16x8*)((const char*)Vtb + nf * 2048 + q * 128 + voff[1]);
#pragma unroll
      for (int qg = 0; qg < 2; ++qg) {
        acc_o[qg][nf] = __builtin_amdgcn_mfma_f32_16x16x32_bf16(pa[qg][0], vb0, acc_o[qg][nf], 0, 0, 0);
        acc_o[qg][nf] = __builtin_amdgcn_mfma_f32_16x16x32_bf16(pa[qg][1], vb1, acc_o[qg][nf], 0, 0, 0);
      }
    }
    __builtin_amdgcn_s_setprio(0);
  };

  // prologue: stage tile 0 into buffer 0
  STAGE(0, 0);
  __syncthreads();  // vmcnt drain + barrier: buffer 0 ready

  // main loop, unrolled x2 so buffer indices are compile-time
  for (int t = 0; t < S_LEN / 64; t += 2) {
    STAGE(1, t + 1);              // issue next tile while computing current
    COMPUTE(Ks[0], Vt[0]);
    __syncthreads();              // drain staged loads; all done reading buf0

    if (t + 2 < S_LEN / 64) STAGE(0, t + 2);
    COMPUTE(Ks[1], Vt[1]);
    __syncthreads();
  }

  // epilogue: reduce l across kg groups once, normalize, split, write.
  const int b = bh >> 4, h = bh & 15;
#pragma unroll
  for (int qg = 0; qg < 2; ++qg) {
    float ps = l_s[qg];
    ps += __shfl_xor(ps, 16);
    ps += __shfl_xor(ps, 32);
    const float linv = 1.0f / ps;
    float ir[4];
#pragma unroll
    for (int r = 0; r < 4; ++r) ir[r] = __shfl(linv, (kg << 2) | r, 64);
#pragma unroll
    for (int nf = 0; nf < 4; ++nf) {
#pragma unroll
      for (int r = 0; r < 4; ++r) {
        const float val = acc_o[qg][nf][r] * ir[r];
        const __bf16 hb = (__bf16)val;
        const __bf16 lb = (__bf16)(val - (float)hb);
        const size_t row = (size_t)b * S_LEN + q0 + w * 32 + qg * 16 + (kg << 2) + r;
        const size_t col = (size_t)h * 64 + nf * 16 + q;
        o_hi[row * 1024 + col] = hb;
        o_lo[row * 1024 + col] = lb;
      }
    }
  }
}

// ---------------------------------------------------------------------------
extern "C" void kernel_launch(void* const* d_in, const int* in_sizes, int n_in,
                              void* d_out, int out_size, void* d_ws, size_t ws_size,
                              hipStream_t stream) {
  const float* x  = (const float*)d_in[0];
  const float* Wq = (const float*)d_in[1];
  const float* bq = (const float*)d_in[2];
  const float* Wk = (const float*)d_in[3];
  const float* bk = (const float*)d_in[4];
  const float* Wv = (const float*)d_in[5];
  const float* bv = (const float*)d_in[6];
  const float* Wo = (const float*)d_in[7];
  const float* bo = (const float*)d_in[8];
  float* out = (float*)d_out;

  char* ws = (char*)d_ws;
  const size_t XB = 16777216ull;  // 8192*1024*2 bytes
  __bf16* x_hi  = (__bf16*)(ws);                 // reused as o_hi after V-proj
  __bf16* x_lo  = (__bf16*)(ws + XB);            // reused as o_lo
  __bf16* qbuf  = (__bf16*)(ws + 2 * XB);
  __bf16* kbuf  = (__bf16*)(ws + 3 * XB);
  __bf16* vbufT = (__bf16*)(ws + 4 * XB);
  __bf16* wt    = (__bf16*)(ws + 5 * XB);
  const size_t WE = 1048576ull;  // 1024*1024 elements per weight matrix
  __bf16* wtq_h = wt + 0 * WE; __bf16* wtq_l = wt + 1 * WE;
  __bf16* wtk_h = wt + 2 * WE; __bf16* wtk_l = wt + 3 * WE;
  __bf16* wtv_h = wt + 4 * WE; __bf16* wtv_l = wt + 5 * WE;
  __bf16* wto_h = wt + 6 * WE; __bf16* wto_l = wt + 7 * WE;

  split_x_kernel<<<8192, 256, 0, stream>>>(x, x_hi, x_lo);
  tsplit_w_kernel<<<dim3(32, 32), 256, 0, stream>>>(Wq, wtq_h, wtq_l);
  tsplit_w_kernel<<<dim3(32, 32), 256, 0, stream>>>(Wk, wtk_h, wtk_l);
  tsplit_w_kernel<<<dim3(32, 32), 256, 0, stream>>>(Wv, wtv_h, wtv_l);
  tsplit_w_kernel<<<dim3(32, 32), 256, 0, stream>>>(Wo, wto_h, wto_l);

  const dim3 gg(64, 8);
  // Q: fold 1/sqrt(64) * log2(e) into the projection (applied in fp32)
  gemm_bf16x3_kernel<<<gg, 256, 0, stream>>>(x_hi, x_lo, wtq_h, wtq_l, bq,
                                             nullptr, qbuf, 1, 0.18033688011112042f);
  gemm_bf16x3_kernel<<<gg, 256, 0, stream>>>(x_hi, x_lo, wtk_h, wtk_l, bk,
                                             nullptr, kbuf, 1, 1.0f);
  gemm_bf16x3_kernel<<<gg, 256, 0, stream>>>(x_hi, x_lo, wtv_h, wtv_l, bv,
                                             nullptr, vbufT, 2, 1.0f);
  attn_mfma_kernel<<<dim3(16, 64), 256, 0, stream>>>(qbuf, kbuf, vbufT, x_hi, x_lo);
  gemm_bf16x3_kernel<<<gg, 256, 0, stream>>>(x_hi, x_lo, wto_h, wto_l, bo,
                                             out, nullptr, 0, 1.0f);
}